// Round 1
// baseline (3041.884 us; speedup 1.0000x reference)
//
#include <hip/hip_runtime.h>
#include <hip/hip_bf16.h>
#include <math.h>

// Problem constants
#define NB 16      // batch
#define NA 64      // atoms
#define NC 32      // channels
#define NLVL 4
#define NSLOT 16   // 1+3+5+7 spherical slots
#define NBAS 60

// ws layout (in floats)
#define OFF_REP   0            // 5 * 16*64*16*32 = 5*524288
#define REPSZ     524288
#define OFF_EDGE  2621440      // 16*64*64*4*32 = 8388608
#define OFF_CUT   11010048     // 65536
#define OFF_SPH   11075584     // 1024 rows * 16 * 64 = 1048576
#define OFF_BASIS 12124160     // 1024 rows * 64 * 60 = 3932160

// ---------------- P1: init rep buffer 0 (a0 into slot 0, zeros elsewhere) ---
__global__ void k_init(const float* __restrict__ oh, const int* __restrict__ chg,
                       const float* __restrict__ Win, const float* __restrict__ bin,
                       float* __restrict__ rep0) {
  int idx = blockIdx.x * 256 + threadIdx.x;           // over 16*64*16*32
  if (idx >= NB * NA * NSLOT * NC) return;
  int c = idx & 31;
  int s = (idx >> 5) & 15;
  int bn = idx >> 9;
  float v = 0.f;
  if (s == 0) {
    float ch = (float)chg[bn] / 9.0f;
    float p1 = ch, p2 = ch * ch;
    v = bin[c];
    #pragma unroll
    for (int sp = 0; sp < 5; sp++) {
      float o = oh[bn * 5 + sp];
      v += o * (Win[(sp * 3 + 0) * 32 + c] + p1 * Win[(sp * 3 + 1) * 32 + c] +
                p2 * Win[(sp * 3 + 2) * 32 + c]);
    }
  }
  rep0[idx] = v;
}

// ---------------- P2: per-edge geometry (cutoff, sph, basis) ----------------
__global__ void k_geom(const float* __restrict__ pos, float* __restrict__ cut,
                       float* __restrict__ sph, float* __restrict__ basis) {
  int row = blockIdx.x;            // b*64 + i
  int j = threadIdx.x;             // 0..63
  int b = row >> 6, i = row & 63;
  float xi = pos[(b * 64 + i) * 3 + 0];
  float yi = pos[(b * 64 + i) * 3 + 1];
  float zi = pos[(b * 64 + i) * 3 + 2];
  float xj = pos[(b * 64 + j) * 3 + 0];
  float yj = pos[(b * 64 + j) * 3 + 1];
  float zj = pos[(b * 64 + j) * 3 + 2];
  float rx = xi - xj, ry = yi - yj, rz = zi - zj;
  float n2 = rx * rx + ry * ry + rz * rz + 1e-12f;
  float r = sqrtf(n2);
  float inv = 1.0f / r;
  float x = rx * inv, y = ry * inv, z = rz * inv;
  // cutoff = emask * (r>1e-4) * (r<5) * sigmoid((3-r)/0.5)
  float cu = 0.f;
  if (i != j && r > 1e-4f && r < 5.0f)
    cu = 1.0f / (1.0f + expf((r - 3.0f) * 2.0f));
  cut[row * 64 + j] = cu;
  // spherical harmonics, slots: l0:[0], l1:[1..3], l2:[4..8], l3:[9..15]
  float s[16];
  s[0] = 1.0f;
  s[1] = x; s[2] = y; s[3] = z;
  s[4] = x * y; s[5] = y * z; s[6] = 3.f * z * z - 1.f; s[7] = x * z; s[8] = x * x - y * y;
  s[9]  = y * (3.f * x * x - y * y);
  s[10] = x * y * z;
  s[11] = y * (5.f * z * z - 1.f);
  s[12] = z * (5.f * z * z - 3.f);
  s[13] = x * (5.f * z * z - 1.f);
  s[14] = z * (x * x - y * y);
  s[15] = x * (x * x - 3.f * y * y);
  #pragma unroll
  for (int m = 0; m < 16; m++) sph[(row * 16 + m) * 64 + j] = s[m];
  // gaussian basis -> LDS, then coalesced store. layout [row][j][60]
  __shared__ float sb[64 * 60];
  #pragma unroll 4
  for (int k = 0; k < 60; k++) {
    float ck = 5.0f * (float)k / 59.0f;
    float d = r - ck;
    sb[j * 60 + k] = expf(-36.0f * d * d);
  }
  __syncthreads();
  float* dst = basis + row * 3840;
  for (int t = j; t < 3840; t += 64) dst[t] = sb[t];
}

// ---------------- L: one message-passing level ------------------------------
__global__ __launch_bounds__(256)
void k_level(int lvl, const float* __restrict__ Wrad, const float* __restrict__ Wedge,
             const float* __restrict__ Wagg, const float* __restrict__ Wself,
             const float* __restrict__ repPrev, float* __restrict__ repNext,
             float* __restrict__ edge, const float* __restrict__ cut,
             const float* __restrict__ sph, const float* __restrict__ basisG) {
  __shared__ float sWradT[4][32][60];   // [l][c][k]   30720 B
  __shared__ float sWtT[4][32][36];     // [l][c][d]   18432 B (pad 36 for b128 + banks)
  __shared__ float sRep0[64][32];       // [j][d]       8192 B
  __shared__ float sBasisMsg[4096];     // phaseA: basis[j*60+k] (3840); phaseB: msg[8][16][32]
  __shared__ float sSph[16][64];        //              4096 B
  __shared__ float sCut[64];
  __shared__ float sMsgS[16][32];       // reduced msg  2048 B

  int row = blockIdx.x;                 // b*64 + i
  int b = row >> 6;
  int tid = threadIdx.x;

  // ---- stage weights / row data ----
  for (int idx = tid; idx < 7680; idx += 256) {
    int l = idx / 1920, rem = idx % 1920, k = rem / 32, c = rem % 32;
    sWradT[l][c][k] = Wrad[((lvl * 4 + l) * 60 + k) * 32 + c];
  }
  const float* repI = repPrev + (row * 16 + 0) * 32;   // rep0_i[d]
  for (int idx = tid; idx < 4096; idx += 256) {
    int l = idx >> 10, rem = idx & 1023, d = rem >> 5, c = rem & 31;
    sWtT[l][c][d] = repI[d] * Wedge[((lvl * 4 + l) * 32 + d) * 32 + c];
  }
  for (int idx = tid; idx < 2048; idx += 256) {
    int j = idx >> 5, d = idx & 31;
    sRep0[j][d] = repPrev[((b * 64 + j) * 16 + 0) * 32 + d];
  }
  for (int idx = tid; idx < 3840; idx += 256) sBasisMsg[idx] = basisG[row * 3840 + idx];
  for (int idx = tid; idx < 1024; idx += 256) (&sSph[0][0])[idx] = sph[row * 1024 + idx];
  if (tid < 64) sCut[tid] = cut[row * 64 + tid];
  __syncthreads();

  // ---- phase A: edges + in-register msg partials ----
  int c = tid & 31, jg = tid >> 5;      // 32 channels x 8 j-groups (Tj=8)
  float msg[16];
  #pragma unroll
  for (int t = 0; t < 16; t++) msg[t] = 0.f;

  #pragma unroll
  for (int l = 0; l < 4; l++) {
    const int base = (l == 0) ? 0 : (l == 1) ? 1 : (l == 2) ? 4 : 9;
    float rad[8], ev[8];
    #pragma unroll
    for (int jj = 0; jj < 8; jj++) { rad[jj] = 0.f; ev[jj] = 0.f; }
    for (int k0 = 0; k0 < 60; k0 += 4) {
      const float4 w = *(const float4*)&sWradT[l][c][k0];
      #pragma unroll
      for (int jj = 0; jj < 8; jj++) {
        const float4 bv = *(const float4*)&sBasisMsg[(jg * 8 + jj) * 60 + k0];
        rad[jj] += bv.x * w.x + bv.y * w.y + bv.z * w.z + bv.w * w.w;
      }
    }
    for (int d0 = 0; d0 < 32; d0 += 4) {
      const float4 w = *(const float4*)&sWtT[l][c][d0];
      #pragma unroll
      for (int jj = 0; jj < 8; jj++) {
        const float4 rv = *(const float4*)&sRep0[jg * 8 + jj][d0];
        ev[jj] += rv.x * w.x + rv.y * w.y + rv.z * w.z + rv.w * w.w;
      }
    }
    #pragma unroll
    for (int jj = 0; jj < 8; jj++) {
      int j = jg * 8 + jj;
      int eidx = ((row * 64 + j) * 4 + l) * 32 + c;
      float e = ev[jj];
      if (lvl > 0) e += edge[eidx];        // previous level's edge_net[l]
      float val = sCut[j] * rad[jj] * e;
      edge[eidx] = val;
      #pragma unroll
      for (int m = 0; m < 2 * l + 1; m++)
        msg[base + m] += val * sSph[base + m][j];
    }
  }
  __syncthreads();   // done reading basis; alias region as msg buffer

  // ---- phase B: reduce msg over j-groups ----
  float* sMsg = sBasisMsg;               // [8][16][32]
  #pragma unroll
  for (int t = 0; t < 16; t++) sMsg[(jg * 16 + t) * 32 + c] = msg[t];
  __syncthreads();
  for (int o = tid; o < 512; o += 256) {
    int lm = o >> 5, cc = o & 31;
    float acc = 0.f;
    #pragma unroll
    for (int g = 0; g < 8; g++) acc += sMsg[(g * 16 + lm) * 32 + cc];
    sMsgS[lm][cc] = acc;
  }
  __syncthreads();

  // ---- phase C: rep_new = msg@W_agg + rep_prev@W_self ----
  int d = tid & 31, lmg = tid >> 5;
  #pragma unroll
  for (int t = 0; t < 2; t++) {
    int lm = lmg + t * 8;
    int l = (lm == 0) ? 0 : (lm < 4) ? 1 : (lm < 9) ? 2 : 3;
    const float* Wa = Wagg + (lvl * 4 + l) * 32 * 32;     // [c][d]
    const float* Ws = Wself + (lvl * 4 + l) * 32 * 32;
    float acc = 0.f;
    for (int cc = 0; cc < 32; cc++) {
      acc += sMsgS[lm][cc] * Wa[cc * 32 + d];
      acc += repPrev[(row * 16 + lm) * 32 + cc] * Ws[cc * 32 + d];
    }
    repNext[(row * 16 + lm) * 32 + d] = acc;
  }
}

// ---------------- F: scalars + pooled linear head ---------------------------
__global__ void k_final(const float* __restrict__ repAll, const float* __restrict__ Wtop,
                        const float* __restrict__ btop, float* __restrict__ out) {
  int b = blockIdx.x;
  int tid = threadIdx.x;
  __shared__ float red[256];
  float partial = 0.f;
  for (int f = tid; f < 512; f += 256) {
    int lvl = f >> 7;
    int rem = f & 127;
    int l = rem >> 5;
    int c = rem & 31;
    const float* repB = repAll + (lvl + 1) * REPSZ;
    int base = (l == 0) ? 0 : (l == 1) ? 1 : (l == 2) ? 4 : 9;
    float acc = 0.f;
    for (int n = 0; n < 64; n++) {
      int ro = (b * 64 + n) * 16;
      float v;
      if (l == 0) {
        v = repB[(ro + 0) * 32 + c];
      } else {
        float s2 = 0.f;
        for (int m = 0; m < 2 * l + 1; m++) {
          float t = repB[(ro + base + m) * 32 + c];
          s2 += t * t;
        }
        v = sqrtf(s2 + 1e-12f);
      }
      acc += v;
    }
    partial += acc * Wtop[f];
  }
  red[tid] = partial;
  __syncthreads();
  for (int s = 128; s > 0; s >>= 1) {
    if (tid < s) red[tid] += red[tid + s];
    __syncthreads();
  }
  if (tid == 0) out[b] = red[0] + btop[0];
}

// ---------------- launch ----------------------------------------------------
extern "C" void kernel_launch(void* const* d_in, const int* in_sizes, int n_in,
                              void* d_out, int out_size, void* d_ws, size_t ws_size,
                              hipStream_t stream) {
  const float* positions = (const float*)d_in[0];
  const float* one_hot   = (const float*)d_in[1];
  const int*   charges   = (const int*)d_in[2];
  // d_in[3] atom_mask (all true), d_in[4] edge_mask (~eye): folded into cutoff
  const float* W_in   = (const float*)d_in[5];
  const float* b_in   = (const float*)d_in[6];
  const float* W_rad  = (const float*)d_in[7];
  const float* W_edge = (const float*)d_in[8];
  const float* W_agg  = (const float*)d_in[9];
  const float* W_self = (const float*)d_in[10];
  const float* W_top  = (const float*)d_in[11];
  const float* b_top  = (const float*)d_in[12];
  float* out = (float*)d_out;
  float* ws = (float*)d_ws;

  float* rep    = ws + OFF_REP;     // 5 buffers of 524288
  float* edge   = ws + OFF_EDGE;
  float* cutp   = ws + OFF_CUT;
  float* sphp   = ws + OFF_SPH;
  float* basisp = ws + OFF_BASIS;

  k_init<<<2048, 256, 0, stream>>>(one_hot, charges, W_in, b_in, rep);
  k_geom<<<1024, 64, 0, stream>>>(positions, cutp, sphp, basisp);
  for (int lvl = 0; lvl < NLVL; lvl++) {
    k_level<<<1024, 256, 0, stream>>>(lvl, W_rad, W_edge, W_agg, W_self,
                                      rep + lvl * REPSZ, rep + (lvl + 1) * REPSZ,
                                      edge, cutp, sphp, basisp);
  }
  k_final<<<16, 256, 0, stream>>>(rep, W_top, b_top, out);
}

// Round 2
// 937.549 us; speedup vs baseline: 3.2445x; 3.2445x over previous
//
#include <hip/hip_runtime.h>
#include <hip/hip_bf16.h>
#include <math.h>

// Problem constants
#define NB 16      // batch
#define NA 64      // atoms
#define NC 32      // channels
#define NLVL 4
#define NSLOT 16   // 1+3+5+7 spherical slots
#define NBAS 60

// ws layout (in floats)
#define OFF_REP   0            // 5 * 16*64*16*32 = 5*524288
#define REPSZ     524288
#define OFF_EDGE  2621440      // 16*64*64*4*32 = 8388608
#define OFF_CUT   11010048     // 65536
#define OFF_SPH   11075584     // 1024 rows * 16 * 64 = 1048576
#define OFF_BASIS 12124160     // 1024 rows * 64 * 60 = 3932160

// ---------------- P1: init rep buffer 0 (a0 into slot 0, zeros elsewhere) ---
__global__ void k_init(const float* __restrict__ oh, const int* __restrict__ chg,
                       const float* __restrict__ Win, const float* __restrict__ bin,
                       float* __restrict__ rep0) {
  int idx = blockIdx.x * 256 + threadIdx.x;           // over 16*64*16*32
  if (idx >= NB * NA * NSLOT * NC) return;
  int c = idx & 31;
  int s = (idx >> 5) & 15;
  int bn = idx >> 9;
  float v = 0.f;
  if (s == 0) {
    float ch = (float)chg[bn] / 9.0f;
    float p1 = ch, p2 = ch * ch;
    v = bin[c];
    #pragma unroll
    for (int sp = 0; sp < 5; sp++) {
      float o = oh[bn * 5 + sp];
      v += o * (Win[(sp * 3 + 0) * 32 + c] + p1 * Win[(sp * 3 + 1) * 32 + c] +
                p2 * Win[(sp * 3 + 2) * 32 + c]);
    }
  }
  rep0[idx] = v;
}

// ---------------- P2: per-edge geometry (cutoff, sph, basis) ----------------
__global__ void k_geom(const float* __restrict__ pos, float* __restrict__ cut,
                       float* __restrict__ sph, float* __restrict__ basis) {
  int row = blockIdx.x;            // b*64 + i
  int j = threadIdx.x;             // 0..63
  int b = row >> 6, i = row & 63;
  float xi = pos[(b * 64 + i) * 3 + 0];
  float yi = pos[(b * 64 + i) * 3 + 1];
  float zi = pos[(b * 64 + i) * 3 + 2];
  float xj = pos[(b * 64 + j) * 3 + 0];
  float yj = pos[(b * 64 + j) * 3 + 1];
  float zj = pos[(b * 64 + j) * 3 + 2];
  float rx = xi - xj, ry = yi - yj, rz = zi - zj;
  float n2 = rx * rx + ry * ry + rz * rz + 1e-12f;
  float r = sqrtf(n2);
  float inv = 1.0f / r;
  float x = rx * inv, y = ry * inv, z = rz * inv;
  // cutoff = emask * (r>1e-4) * (r<5) * sigmoid((3-r)/0.5)
  float cu = 0.f;
  if (i != j && r > 1e-4f && r < 5.0f)
    cu = 1.0f / (1.0f + expf((r - 3.0f) * 2.0f));
  cut[row * 64 + j] = cu;
  // spherical harmonics, slots: l0:[0], l1:[1..3], l2:[4..8], l3:[9..15]
  float s[16];
  s[0] = 1.0f;
  s[1] = x; s[2] = y; s[3] = z;
  s[4] = x * y; s[5] = y * z; s[6] = 3.f * z * z - 1.f; s[7] = x * z; s[8] = x * x - y * y;
  s[9]  = y * (3.f * x * x - y * y);
  s[10] = x * y * z;
  s[11] = y * (5.f * z * z - 1.f);
  s[12] = z * (5.f * z * z - 3.f);
  s[13] = x * (5.f * z * z - 1.f);
  s[14] = z * (x * x - y * y);
  s[15] = x * (x * x - 3.f * y * y);
  #pragma unroll
  for (int m = 0; m < 16; m++) sph[(row * 16 + m) * 64 + j] = s[m];
  // gaussian basis -> LDS, then coalesced store. layout [row][j][60]
  __shared__ float sb[64 * 60];
  #pragma unroll 4
  for (int k = 0; k < 60; k++) {
    float ck = 5.0f * (float)k / 59.0f;
    float d = r - ck;
    sb[j * 60 + k] = expf(-36.0f * d * d);
  }
  __syncthreads();
  float* dst = basis + row * 3840;
  for (int t = j; t < 3840; t += 64) dst[t] = sb[t];
}

// ---------------- L: one message-passing level ------------------------------
__global__ __launch_bounds__(256)
void k_level(int lvl, const float* __restrict__ Wrad, const float* __restrict__ Wedge,
             const float* __restrict__ Wagg, const float* __restrict__ Wself,
             const float* __restrict__ repPrev, float* __restrict__ repNext,
             float* __restrict__ edge, const float* __restrict__ cut,
             const float* __restrict__ sph, const float* __restrict__ basisG) {
  __shared__ float sWradT[4][32][60];   // [l][c][k]   30720 B
  __shared__ float sWtT[4][32][36];     // [l][c][d]   18432 B (pad 36 for b128 + banks)
  __shared__ float sRep0[64][32];       // [j][d]       8192 B
  __shared__ float sBasisMsg[4096];     // phaseA: basis[j*60+k] (3840); phaseB: msg[8][16][32]
  __shared__ float sSph[16][64];        //              4096 B
  __shared__ float sCut[64];
  __shared__ float sMsgS[16][32];       // reduced msg  2048 B

  int row = blockIdx.x;                 // b*64 + i
  int b = row >> 6;
  int tid = threadIdx.x;

  // ---- stage weights / row data ----
  for (int idx = tid; idx < 7680; idx += 256) {
    int l = idx / 1920, rem = idx % 1920, k = rem / 32, c = rem % 32;
    sWradT[l][c][k] = Wrad[((lvl * 4 + l) * 60 + k) * 32 + c];
  }
  const float* repI = repPrev + (row * 16 + 0) * 32;   // rep0_i[d]
  for (int idx = tid; idx < 4096; idx += 256) {
    int l = idx >> 10, rem = idx & 1023, d = rem >> 5, c = rem & 31;
    sWtT[l][c][d] = repI[d] * Wedge[((lvl * 4 + l) * 32 + d) * 32 + c];
  }
  for (int idx = tid; idx < 2048; idx += 256) {
    int j = idx >> 5, d = idx & 31;
    sRep0[j][d] = repPrev[((b * 64 + j) * 16 + 0) * 32 + d];
  }
  for (int idx = tid; idx < 3840; idx += 256) sBasisMsg[idx] = basisG[row * 3840 + idx];
  for (int idx = tid; idx < 1024; idx += 256) (&sSph[0][0])[idx] = sph[row * 1024 + idx];
  if (tid < 64) sCut[tid] = cut[row * 64 + tid];
  __syncthreads();

  // ---- phase A: edges + in-register msg partials ----
  // 32 channels x 8 j-groups; each j-group's 8 edges processed in TWO
  // sequential Tj=4 passes to keep the live register set small (R1: Tj=8
  // with everything unrolled spilled rad[]/ev[] -> 1.4 GB scratch writes).
  int c = tid & 31, jg = tid >> 5;
  float msg[16];
  #pragma unroll
  for (int t = 0; t < 16; t++) msg[t] = 0.f;

  #pragma unroll
  for (int l = 0; l < 4; l++) {
    const int base = (l == 0) ? 0 : (l == 1) ? 1 : (l == 2) ? 4 : 9;
    #pragma unroll 1
    for (int jt = 0; jt < 8; jt += 4) {       // two Tj=4 passes, NOT unrolled
      float rad[4] = {0.f, 0.f, 0.f, 0.f};
      for (int k0 = 0; k0 < 60; k0 += 4) {
        const float4 w = *(const float4*)&sWradT[l][c][k0];
        #pragma unroll
        for (int jj = 0; jj < 4; jj++) {
          const float4 bv = *(const float4*)&sBasisMsg[(jg * 8 + jt + jj) * 60 + k0];
          rad[jj] += bv.x * w.x + bv.y * w.y + bv.z * w.z + bv.w * w.w;
        }
      }
      float ev[4] = {0.f, 0.f, 0.f, 0.f};
      #pragma unroll
      for (int d0 = 0; d0 < 32; d0 += 4) {
        const float4 w = *(const float4*)&sWtT[l][c][d0];
        #pragma unroll
        for (int jj = 0; jj < 4; jj++) {
          const float4 rv = *(const float4*)&sRep0[jg * 8 + jt + jj][d0];
          ev[jj] += rv.x * w.x + rv.y * w.y + rv.z * w.z + rv.w * w.w;
        }
      }
      #pragma unroll
      for (int jj = 0; jj < 4; jj++) {
        int j = jg * 8 + jt + jj;
        int eidx = ((row * 64 + j) * 4 + l) * 32 + c;
        float e = ev[jj];
        if (lvl > 0) e += edge[eidx];        // previous level's edge_net[l]
        float val = sCut[j] * rad[jj] * e;
        edge[eidx] = val;
        #pragma unroll
        for (int m = 0; m < 2 * l + 1; m++)
          msg[base + m] += val * sSph[base + m][j];
      }
    }
  }
  __syncthreads();   // done reading basis; alias region as msg buffer

  // ---- phase B: reduce msg over j-groups ----
  float* sMsg = sBasisMsg;               // [8][16][32]
  #pragma unroll
  for (int t = 0; t < 16; t++) sMsg[(jg * 16 + t) * 32 + c] = msg[t];
  __syncthreads();
  for (int o = tid; o < 512; o += 256) {
    int lm = o >> 5, cc = o & 31;
    float acc = 0.f;
    #pragma unroll
    for (int g = 0; g < 8; g++) acc += sMsg[(g * 16 + lm) * 32 + cc];
    sMsgS[lm][cc] = acc;
  }
  __syncthreads();

  // ---- phase C: rep_new = msg@W_agg + rep_prev@W_self ----
  int d = tid & 31, lmg = tid >> 5;
  #pragma unroll
  for (int t = 0; t < 2; t++) {
    int lm = lmg + t * 8;
    int l = (lm == 0) ? 0 : (lm < 4) ? 1 : (lm < 9) ? 2 : 3;
    const float* Wa = Wagg + (lvl * 4 + l) * 32 * 32;     // [c][d]
    const float* Ws = Wself + (lvl * 4 + l) * 32 * 32;
    float acc = 0.f;
    for (int cc = 0; cc < 32; cc++) {
      acc += sMsgS[lm][cc] * Wa[cc * 32 + d];
      acc += repPrev[(row * 16 + lm) * 32 + cc] * Ws[cc * 32 + d];
    }
    repNext[(row * 16 + lm) * 32 + d] = acc;
  }
}

// ---------------- F: scalars + pooled linear head ---------------------------
__global__ void k_final(const float* __restrict__ repAll, const float* __restrict__ Wtop,
                        const float* __restrict__ btop, float* __restrict__ out) {
  int b = blockIdx.x;
  int tid = threadIdx.x;
  __shared__ float red[256];
  float partial = 0.f;
  for (int f = tid; f < 512; f += 256) {
    int lvl = f >> 7;
    int rem = f & 127;
    int l = rem >> 5;
    int c = rem & 31;
    const float* repB = repAll + (lvl + 1) * REPSZ;
    int base = (l == 0) ? 0 : (l == 1) ? 1 : (l == 2) ? 4 : 9;
    float acc = 0.f;
    for (int n = 0; n < 64; n++) {
      int ro = (b * 64 + n) * 16;
      float v;
      if (l == 0) {
        v = repB[(ro + 0) * 32 + c];
      } else {
        float s2 = 0.f;
        for (int m = 0; m < 2 * l + 1; m++) {
          float t = repB[(ro + base + m) * 32 + c];
          s2 += t * t;
        }
        v = sqrtf(s2 + 1e-12f);
      }
      acc += v;
    }
    partial += acc * Wtop[f];
  }
  red[tid] = partial;
  __syncthreads();
  for (int s = 128; s > 0; s >>= 1) {
    if (tid < s) red[tid] += red[tid + s];
    __syncthreads();
  }
  if (tid == 0) out[b] = red[0] + btop[0];
}

// ---------------- launch ----------------------------------------------------
extern "C" void kernel_launch(void* const* d_in, const int* in_sizes, int n_in,
                              void* d_out, int out_size, void* d_ws, size_t ws_size,
                              hipStream_t stream) {
  const float* positions = (const float*)d_in[0];
  const float* one_hot   = (const float*)d_in[1];
  const int*   charges   = (const int*)d_in[2];
  // d_in[3] atom_mask (all true), d_in[4] edge_mask (~eye): folded into cutoff
  const float* W_in   = (const float*)d_in[5];
  const float* b_in   = (const float*)d_in[6];
  const float* W_rad  = (const float*)d_in[7];
  const float* W_edge = (const float*)d_in[8];
  const float* W_agg  = (const float*)d_in[9];
  const float* W_self = (const float*)d_in[10];
  const float* W_top  = (const float*)d_in[11];
  const float* b_top  = (const float*)d_in[12];
  float* out = (float*)d_out;
  float* ws = (float*)d_ws;

  float* rep    = ws + OFF_REP;     // 5 buffers of 524288
  float* edge   = ws + OFF_EDGE;
  float* cutp   = ws + OFF_CUT;
  float* sphp   = ws + OFF_SPH;
  float* basisp = ws + OFF_BASIS;

  k_init<<<2048, 256, 0, stream>>>(one_hot, charges, W_in, b_in, rep);
  k_geom<<<1024, 64, 0, stream>>>(positions, cutp, sphp, basisp);
  for (int lvl = 0; lvl < NLVL; lvl++) {
    k_level<<<1024, 256, 0, stream>>>(lvl, W_rad, W_edge, W_agg, W_self,
                                      rep + lvl * REPSZ, rep + (lvl + 1) * REPSZ,
                                      edge, cutp, sphp, basisp);
  }
  k_final<<<16, 256, 0, stream>>>(rep, W_top, b_top, out);
}

// Round 3
// 594.627 us; speedup vs baseline: 5.1156x; 1.5767x over previous
//
#include <hip/hip_runtime.h>
#include <hip/hip_bf16.h>
#include <math.h>

// Problem constants
#define NB 16      // batch
#define NA 64      // atoms
#define NC 32      // channels
#define NLVL 4
#define NSLOT 16   // 1+3+5+7 spherical slots
#define NBAS 60

// ws layout (in floats)
#define OFF_REP   0            // 5 * 16*64*16*32 = 5*524288
#define REPSZ     524288
#define OFF_EDGE  2621440      // 16*64*64*4*32 = 8388608
#define OFF_CUT   11010048     // 65536
#define OFF_SPH   11075584     // 1024 rows * 16 * 64 = 1048576
#define OFF_BASIS 12124160     // 1024 rows * 64 * 60 = 3932160
// after levels complete, edge region is dead -> reuse for per-atom partials
#define OFF_PART  OFF_EDGE     // 1024 floats

// ---------------- P1: init rep buffer 0 (a0 into slot 0, zeros elsewhere) ---
__global__ void k_init(const float* __restrict__ oh, const int* __restrict__ chg,
                       const float* __restrict__ Win, const float* __restrict__ bin,
                       float* __restrict__ rep0) {
  int idx = blockIdx.x * 256 + threadIdx.x;           // over 16*64*16*32
  if (idx >= NB * NA * NSLOT * NC) return;
  int c = idx & 31;
  int s = (idx >> 5) & 15;
  int bn = idx >> 9;
  float v = 0.f;
  if (s == 0) {
    float ch = (float)chg[bn] / 9.0f;
    float p1 = ch, p2 = ch * ch;
    v = bin[c];
    #pragma unroll
    for (int sp = 0; sp < 5; sp++) {
      float o = oh[bn * 5 + sp];
      v += o * (Win[(sp * 3 + 0) * 32 + c] + p1 * Win[(sp * 3 + 1) * 32 + c] +
                p2 * Win[(sp * 3 + 2) * 32 + c]);
    }
  }
  rep0[idx] = v;
}

// ---------------- P2: per-edge geometry (cutoff, sph, basis) ----------------
__global__ void k_geom(const float* __restrict__ pos, float* __restrict__ cut,
                       float* __restrict__ sph, float* __restrict__ basis) {
  int row = blockIdx.x;            // b*64 + i
  int j = threadIdx.x;             // 0..63
  int b = row >> 6, i = row & 63;
  float xi = pos[(b * 64 + i) * 3 + 0];
  float yi = pos[(b * 64 + i) * 3 + 1];
  float zi = pos[(b * 64 + i) * 3 + 2];
  float xj = pos[(b * 64 + j) * 3 + 0];
  float yj = pos[(b * 64 + j) * 3 + 1];
  float zj = pos[(b * 64 + j) * 3 + 2];
  float rx = xi - xj, ry = yi - yj, rz = zi - zj;
  float n2 = rx * rx + ry * ry + rz * rz + 1e-12f;
  float r = sqrtf(n2);
  float inv = 1.0f / r;
  float x = rx * inv, y = ry * inv, z = rz * inv;
  // cutoff = emask * (r>1e-4) * (r<5) * sigmoid((3-r)/0.5)
  float cu = 0.f;
  if (i != j && r > 1e-4f && r < 5.0f)
    cu = 1.0f / (1.0f + expf((r - 3.0f) * 2.0f));
  cut[row * 64 + j] = cu;
  // spherical harmonics, slots: l0:[0], l1:[1..3], l2:[4..8], l3:[9..15]
  float s[16];
  s[0] = 1.0f;
  s[1] = x; s[2] = y; s[3] = z;
  s[4] = x * y; s[5] = y * z; s[6] = 3.f * z * z - 1.f; s[7] = x * z; s[8] = x * x - y * y;
  s[9]  = y * (3.f * x * x - y * y);
  s[10] = x * y * z;
  s[11] = y * (5.f * z * z - 1.f);
  s[12] = z * (5.f * z * z - 3.f);
  s[13] = x * (5.f * z * z - 1.f);
  s[14] = z * (x * x - y * y);
  s[15] = x * (x * x - 3.f * y * y);
  #pragma unroll
  for (int m = 0; m < 16; m++) sph[(row * 16 + m) * 64 + j] = s[m];
  // gaussian basis -> LDS, then coalesced store. layout [row][j][60]
  __shared__ float sb[64 * 60];
  #pragma unroll 4
  for (int k = 0; k < 60; k++) {
    float ck = 5.0f * (float)k / 59.0f;
    float d = r - ck;
    sb[j * 60 + k] = expf(-36.0f * d * d);
  }
  __syncthreads();
  float* dst = basis + row * 3840;
  for (int t = j; t < 3840; t += 64) dst[t] = sb[t];
}

// ---------------- L: one message-passing level ------------------------------
__global__ __launch_bounds__(256)
void k_level(int lvl, const float* __restrict__ Wrad, const float* __restrict__ Wedge,
             const float* __restrict__ Wagg, const float* __restrict__ Wself,
             const float* __restrict__ repPrev, float* __restrict__ repNext,
             float* __restrict__ edge, const float* __restrict__ cut,
             const float* __restrict__ sph, const float* __restrict__ basisG) {
  __shared__ float sWradT[4][32][60];   // [l][c][k]   30720 B
  __shared__ float sWtT[4][32][36];     // [l][c][d]   18432 B (pad 36 for b128 align)
  __shared__ float sRep0[64][32];       // [j][d]       8192 B
  __shared__ float sBasisMsg[4096];     // phaseA: basis[j*60+k] (3840); phaseB: msg[8][16][32]
  __shared__ float sSph[16][64];        //              4096 B
  __shared__ float sCut[64];
  __shared__ float sMsgS[16][32];       // reduced msg  2048 B

  int row = blockIdx.x;                 // b*64 + i
  int b = row >> 6;
  int tid = threadIdx.x;

  // ---- stage weights / row data ----
  for (int idx = tid; idx < 7680; idx += 256) {
    int l = idx / 1920, rem = idx % 1920, k = rem / 32, c = rem % 32;
    sWradT[l][c][k] = Wrad[((lvl * 4 + l) * 60 + k) * 32 + c];
  }
  const float* repI = repPrev + (row * 16 + 0) * 32;   // rep0_i[d]
  for (int idx = tid; idx < 4096; idx += 256) {
    int l = idx >> 10, rem = idx & 1023, d = rem >> 5, c = rem & 31;
    sWtT[l][c][d] = repI[d] * Wedge[((lvl * 4 + l) * 32 + d) * 32 + c];
  }
  for (int idx = tid; idx < 2048; idx += 256) {
    int j = idx >> 5, d = idx & 31;
    sRep0[j][d] = repPrev[((b * 64 + j) * 16 + 0) * 32 + d];
  }
  for (int idx = tid; idx < 3840; idx += 256) sBasisMsg[idx] = basisG[row * 3840 + idx];
  for (int idx = tid; idx < 1024; idx += 256) (&sSph[0][0])[idx] = sph[row * 1024 + idx];
  if (tid < 64) sCut[tid] = cut[row * 64 + tid];
  __syncthreads();

  // ---- phase A: edges + in-register msg partials ----
  // k0-OUTER / l-INNER: each basis float4 (broadcast read) feeds all 4 l's,
  // each weight float4 feeds 8 j's. 276 ds_read_b128/thread vs 920 in the
  // l-outer form. Accumulators rad[4][8]+ev[4][8]+msg[16] = 80 VGPR.
  int c = tid & 31, jg = tid >> 5;      // 32 channels x 8 j-groups (Tj=8)
  float msg[16];
  float rad[4][8], ev[4][8];
  #pragma unroll
  for (int t = 0; t < 16; t++) msg[t] = 0.f;
  #pragma unroll
  for (int l = 0; l < 4; l++)
    #pragma unroll
    for (int jj = 0; jj < 8; jj++) { rad[l][jj] = 0.f; ev[l][jj] = 0.f; }

  for (int k0 = 0; k0 < 60; k0 += 4) {
    const float4 w0 = *(const float4*)&sWradT[0][c][k0];
    const float4 w1 = *(const float4*)&sWradT[1][c][k0];
    const float4 w2 = *(const float4*)&sWradT[2][c][k0];
    const float4 w3 = *(const float4*)&sWradT[3][c][k0];
    #pragma unroll
    for (int jj = 0; jj < 8; jj++) {
      const float4 bv = *(const float4*)&sBasisMsg[(jg * 8 + jj) * 60 + k0];
      rad[0][jj] += bv.x * w0.x + bv.y * w0.y + bv.z * w0.z + bv.w * w0.w;
      rad[1][jj] += bv.x * w1.x + bv.y * w1.y + bv.z * w1.z + bv.w * w1.w;
      rad[2][jj] += bv.x * w2.x + bv.y * w2.y + bv.z * w2.z + bv.w * w2.w;
      rad[3][jj] += bv.x * w3.x + bv.y * w3.y + bv.z * w3.z + bv.w * w3.w;
    }
  }
  for (int d0 = 0; d0 < 32; d0 += 4) {
    const float4 w0 = *(const float4*)&sWtT[0][c][d0];
    const float4 w1 = *(const float4*)&sWtT[1][c][d0];
    const float4 w2 = *(const float4*)&sWtT[2][c][d0];
    const float4 w3 = *(const float4*)&sWtT[3][c][d0];
    #pragma unroll
    for (int jj = 0; jj < 8; jj++) {
      const float4 rv = *(const float4*)&sRep0[jg * 8 + jj][d0];
      ev[0][jj] += rv.x * w0.x + rv.y * w0.y + rv.z * w0.z + rv.w * w0.w;
      ev[1][jj] += rv.x * w1.x + rv.y * w1.y + rv.z * w1.z + rv.w * w1.w;
      ev[2][jj] += rv.x * w2.x + rv.y * w2.y + rv.z * w2.z + rv.w * w2.w;
      ev[3][jj] += rv.x * w3.x + rv.y * w3.y + rv.z * w3.z + rv.w * w3.w;
    }
  }
  #pragma unroll
  for (int l = 0; l < 4; l++) {
    const int base = (l == 0) ? 0 : (l == 1) ? 1 : (l == 2) ? 4 : 9;
    #pragma unroll
    for (int jj = 0; jj < 8; jj++) {
      int j = jg * 8 + jj;
      int eidx = ((row * 64 + j) * 4 + l) * 32 + c;
      float e = ev[l][jj];
      if (lvl > 0) e += edge[eidx];        // previous level's edge_net[l]
      float val = sCut[j] * rad[l][jj] * e;
      edge[eidx] = val;
      #pragma unroll
      for (int m = 0; m < 2 * l + 1; m++)
        msg[base + m] += val * sSph[base + m][j];
    }
  }
  __syncthreads();   // done reading basis; alias region as msg buffer

  // ---- phase B: reduce msg over j-groups ----
  float* sMsg = sBasisMsg;               // [8][16][32]
  #pragma unroll
  for (int t = 0; t < 16; t++) sMsg[(jg * 16 + t) * 32 + c] = msg[t];
  __syncthreads();
  for (int o = tid; o < 512; o += 256) {
    int lm = o >> 5, cc = o & 31;
    float acc = 0.f;
    #pragma unroll
    for (int g = 0; g < 8; g++) acc += sMsg[(g * 16 + lm) * 32 + cc];
    sMsgS[lm][cc] = acc;
  }
  __syncthreads();

  // ---- phase C: rep_new = msg@W_agg + rep_prev@W_self ----
  int d = tid & 31, lmg = tid >> 5;
  #pragma unroll
  for (int t = 0; t < 2; t++) {
    int lm = lmg + t * 8;
    int l = (lm == 0) ? 0 : (lm < 4) ? 1 : (lm < 9) ? 2 : 3;
    const float* Wa = Wagg + (lvl * 4 + l) * 32 * 32;     // [c][d]
    const float* Ws = Wself + (lvl * 4 + l) * 32 * 32;
    float acc = 0.f;
    for (int cc = 0; cc < 32; cc++) {
      acc += sMsgS[lm][cc] * Wa[cc * 32 + d];
      acc += repPrev[(row * 16 + lm) * 32 + cc] * Ws[cc * 32 + d];
    }
    repNext[(row * 16 + lm) * 32 + d] = acc;
  }
}

// ---------------- F1: per-atom invariant scalars . W_top -> partial ---------
__global__ void k_scalars(const float* __restrict__ repAll, const float* __restrict__ Wtop,
                          float* __restrict__ partial) {
  int an = blockIdx.x;                  // b*64 + n, 1024 blocks
  int tid = threadIdx.x;                // 128 threads
  __shared__ float red[128];
  float p = 0.f;
  for (int f = tid; f < 512; f += 128) {
    int lvl = f >> 7;
    int rem = f & 127;
    int l = rem >> 5;
    int c = rem & 31;
    const float* repB = repAll + (lvl + 1) * REPSZ + an * 512;   // [16][32] block
    int base = (l == 0) ? 0 : (l == 1) ? 1 : (l == 2) ? 4 : 9;
    float v;
    if (l == 0) {
      v = repB[c];
    } else {
      float s2 = 0.f;
      for (int m = 0; m < 2 * l + 1; m++) {
        float t = repB[(base + m) * 32 + c];
        s2 += t * t;
      }
      v = sqrtf(s2 + 1e-12f);
    }
    p += v * Wtop[f];
  }
  red[tid] = p;
  __syncthreads();
  for (int s = 64; s > 0; s >>= 1) {
    if (tid < s) red[tid] += red[tid + s];
    __syncthreads();
  }
  if (tid == 0) partial[an] = red[0];
}

// ---------------- F2: reduce partials per batch -----------------------------
__global__ void k_out(const float* __restrict__ partial, const float* __restrict__ btop,
                      float* __restrict__ out) {
  int b = blockIdx.x;                   // 16 blocks x 64 threads (1 wave)
  int tid = threadIdx.x;
  float v = partial[b * 64 + tid];
  #pragma unroll
  for (int o = 32; o > 0; o >>= 1) v += __shfl_down(v, o, 64);
  if (tid == 0) out[b] = v + btop[0];
}

// ---------------- launch ----------------------------------------------------
extern "C" void kernel_launch(void* const* d_in, const int* in_sizes, int n_in,
                              void* d_out, int out_size, void* d_ws, size_t ws_size,
                              hipStream_t stream) {
  const float* positions = (const float*)d_in[0];
  const float* one_hot   = (const float*)d_in[1];
  const int*   charges   = (const int*)d_in[2];
  // d_in[3] atom_mask (all true), d_in[4] edge_mask (~eye): folded into cutoff
  const float* W_in   = (const float*)d_in[5];
  const float* b_in   = (const float*)d_in[6];
  const float* W_rad  = (const float*)d_in[7];
  const float* W_edge = (const float*)d_in[8];
  const float* W_agg  = (const float*)d_in[9];
  const float* W_self = (const float*)d_in[10];
  const float* W_top  = (const float*)d_in[11];
  const float* b_top  = (const float*)d_in[12];
  float* out = (float*)d_out;
  float* ws = (float*)d_ws;

  float* rep    = ws + OFF_REP;     // 5 buffers of 524288
  float* edge   = ws + OFF_EDGE;
  float* cutp   = ws + OFF_CUT;
  float* sphp   = ws + OFF_SPH;
  float* basisp = ws + OFF_BASIS;
  float* partial = ws + OFF_PART;   // aliases edge (dead after levels)

  k_init<<<2048, 256, 0, stream>>>(one_hot, charges, W_in, b_in, rep);
  k_geom<<<1024, 64, 0, stream>>>(positions, cutp, sphp, basisp);
  for (int lvl = 0; lvl < NLVL; lvl++) {
    k_level<<<1024, 256, 0, stream>>>(lvl, W_rad, W_edge, W_agg, W_self,
                                      rep + lvl * REPSZ, rep + (lvl + 1) * REPSZ,
                                      edge, cutp, sphp, basisp);
  }
  k_scalars<<<1024, 128, 0, stream>>>(rep, W_top, partial);
  k_out<<<16, 64, 0, stream>>>(partial, b_top, out);
}

// Round 4
// 323.474 us; speedup vs baseline: 9.4038x; 1.8383x over previous
//
#include <hip/hip_runtime.h>
#include <hip/hip_bf16.h>
#include <math.h>

// Problem constants
#define NB 16      // batch
#define NA 64      // atoms
#define NC 32      // channels
#define NLVL 4
#define NSLOT 16   // 1+3+5+7 spherical slots
#define NBAS 60

// ws layout (in floats)
#define OFF_REP   0            // 5 * 16*64*16*32 = 5*524288
#define REPSZ     524288
#define OFF_EDGE  2621440      // 16*64*64*4*32 = 8388608
#define OFF_CUT   11010048     // 65536
#define OFF_SPH   11075584     // 1024 rows * 16 * 64 = 1048576
#define OFF_BASIS 12124160     // 1024 rows * 64 * 60 = 3932160
#define OFF_RAD   16056320     // 1024*64*4*32 = 8388608 (single level, reused)
#define NEED_FLOATS (OFF_RAD + 8388608)
// after levels complete, edge region is dead -> reuse for per-atom partials
#define OFF_PART  OFF_EDGE     // 1024 floats

// ---------------- P1: init rep buffer 0 (a0 into slot 0, zeros elsewhere) ---
__global__ void k_init(const float* __restrict__ oh, const int* __restrict__ chg,
                       const float* __restrict__ Win, const float* __restrict__ bin,
                       float* __restrict__ rep0) {
  int idx = blockIdx.x * 256 + threadIdx.x;           // over 16*64*16*32
  if (idx >= NB * NA * NSLOT * NC) return;
  int c = idx & 31;
  int s = (idx >> 5) & 15;
  int bn = idx >> 9;
  float v = 0.f;
  if (s == 0) {
    float ch = (float)chg[bn] / 9.0f;
    float p1 = ch, p2 = ch * ch;
    v = bin[c];
    #pragma unroll
    for (int sp = 0; sp < 5; sp++) {
      float o = oh[bn * 5 + sp];
      v += o * (Win[(sp * 3 + 0) * 32 + c] + p1 * Win[(sp * 3 + 1) * 32 + c] +
                p2 * Win[(sp * 3 + 2) * 32 + c]);
    }
  }
  rep0[idx] = v;
}

// ---------------- P2: per-edge geometry (cutoff, sph, basis) ----------------
__global__ void k_geom(const float* __restrict__ pos, float* __restrict__ cut,
                       float* __restrict__ sph, float* __restrict__ basis) {
  int row = blockIdx.x;            // b*64 + i
  int j = threadIdx.x;             // 0..63
  int b = row >> 6, i = row & 63;
  float xi = pos[(b * 64 + i) * 3 + 0];
  float yi = pos[(b * 64 + i) * 3 + 1];
  float zi = pos[(b * 64 + i) * 3 + 2];
  float xj = pos[(b * 64 + j) * 3 + 0];
  float yj = pos[(b * 64 + j) * 3 + 1];
  float zj = pos[(b * 64 + j) * 3 + 2];
  float rx = xi - xj, ry = yi - yj, rz = zi - zj;
  float n2 = rx * rx + ry * ry + rz * rz + 1e-12f;
  float r = sqrtf(n2);
  float inv = 1.0f / r;
  float x = rx * inv, y = ry * inv, z = rz * inv;
  float cu = 0.f;
  if (i != j && r > 1e-4f && r < 5.0f)
    cu = 1.0f / (1.0f + expf((r - 3.0f) * 2.0f));
  cut[row * 64 + j] = cu;
  float s[16];
  s[0] = 1.0f;
  s[1] = x; s[2] = y; s[3] = z;
  s[4] = x * y; s[5] = y * z; s[6] = 3.f * z * z - 1.f; s[7] = x * z; s[8] = x * x - y * y;
  s[9]  = y * (3.f * x * x - y * y);
  s[10] = x * y * z;
  s[11] = y * (5.f * z * z - 1.f);
  s[12] = z * (5.f * z * z - 3.f);
  s[13] = x * (5.f * z * z - 1.f);
  s[14] = z * (x * x - y * y);
  s[15] = x * (x * x - 3.f * y * y);
  #pragma unroll
  for (int m = 0; m < 16; m++) sph[(row * 16 + m) * 64 + j] = s[m];
  __shared__ float sb[64 * 60];
  #pragma unroll 4
  for (int k = 0; k < 60; k++) {
    float ck = 5.0f * (float)k / 59.0f;
    float d = r - ck;
    sb[j * 60 + k] = expf(-36.0f * d * d);
  }
  __syncthreads();
  float* dst = basis + row * 3840;
  for (int t = j; t < 3840; t += 64) dst[t] = sb[t];
}

// ---------------- R: radial GEMM for one level: rad = basis @ W_rad[lvl] ----
// rad[row][j][l][c] for all 4 l. Level-recursion-independent.
__global__ __launch_bounds__(256, 3)
void k_rad(int lvl, const float* __restrict__ Wrad, const float* __restrict__ basisG,
           float* __restrict__ rad) {
  __shared__ float sB[64 * 60];       // 15360 B
  __shared__ float sW[4][60][32];     // 30720 B  [l][k][c] natural layout
  int row = blockIdx.x;
  int tid = threadIdx.x;
  int c = tid & 31, jt = tid >> 5;    // 32 channels x 8 j-tiles (8 j each)

  for (int idx = tid; idx < 3840; idx += 256) sB[idx] = basisG[row * 3840 + idx];
  const float* wsrc = Wrad + lvl * 7680;
  float* wdst = &sW[0][0][0];
  for (int idx = tid; idx < 7680; idx += 256) wdst[idx] = wsrc[idx];
  __syncthreads();

  float acc[4][8];
  #pragma unroll
  for (int l = 0; l < 4; l++)
    #pragma unroll
    for (int jj = 0; jj < 8; jj++) acc[l][jj] = 0.f;

  for (int k0 = 0; k0 < 60; k0 += 4) {
    float4 bv[8];
    #pragma unroll
    for (int jj = 0; jj < 8; jj++)
      bv[jj] = *(const float4*)&sB[(jt * 8 + jj) * 60 + k0];
    #pragma unroll
    for (int l = 0; l < 4; l++) {
      float w0 = sW[l][k0 + 0][c];
      float w1 = sW[l][k0 + 1][c];
      float w2 = sW[l][k0 + 2][c];
      float w3 = sW[l][k0 + 3][c];
      #pragma unroll
      for (int jj = 0; jj < 8; jj++)
        acc[l][jj] += bv[jj].x * w0 + bv[jj].y * w1 + bv[jj].z * w2 + bv[jj].w * w3;
    }
  }
  #pragma unroll
  for (int l = 0; l < 4; l++)
    #pragma unroll
    for (int jj = 0; jj < 8; jj++)
      rad[((row * 64 + jt * 8 + jj) * 4 + l) * 32 + c] = acc[l][jj];
}

// ---------------- L: one message-passing level (rad precomputed) ------------
// threads: c = tid&31 (output channel), lidx = (tid>>5)&3, jh = tid>>7.
// LDS ~24.8 KB -> 4 blocks/CU; wt (rep_i-premultiplied W_edge col) in 32 regs.
__global__ __launch_bounds__(256, 4)
void k_level(int lvl, const float* __restrict__ Wedge,
             const float* __restrict__ Wagg, const float* __restrict__ Wself,
             const float* __restrict__ repPrev, float* __restrict__ repNext,
             float* __restrict__ edge, const float* __restrict__ cut,
             const float* __restrict__ sph, const float* __restrict__ radp) {
  __shared__ float sRep0[64][32];     // 8192 B  [j][d]
  __shared__ float sSphP[4][7][64];   // 7168 B  zero-padded sph (static msg idx)
  __shared__ float sCut[64];          // 256 B
  __shared__ float sMsgB[2][4][7][32];// 7168 B  per-jh msg partials
  __shared__ float sMsgS[16][32];     // 2048 B  reduced msg

  int row = blockIdx.x;               // b*64 + i
  int b = row >> 6;
  int tid = threadIdx.x;
  int c = tid & 31, lidx = (tid >> 5) & 3, jh = tid >> 7;
  const int base = (lidx == 0) ? 0 : (lidx == 1) ? 1 : (lidx == 2) ? 4 : 9;

  // ---- stage ----
  for (int idx = tid; idx < 2048; idx += 256) {
    int j = idx >> 5, d = idx & 31;
    sRep0[j][d] = repPrev[((b * 64 + j) * 16 + 0) * 32 + d];
  }
  for (int idx = tid; idx < 1792; idx += 256) {
    int l = idx / 448, rem = idx % 448, m = rem >> 6, j = rem & 63;
    int bs = (l == 0) ? 0 : (l == 1) ? 1 : (l == 2) ? 4 : 9;
    float v = 0.f;
    if (m < 2 * l + 1) v = sph[row * 1024 + (bs + m) * 64 + j];
    sSphP[l][m][j] = v;
  }
  if (tid < 64) sCut[tid] = cut[row * 64 + tid];
  __syncthreads();

  // wt[d] = rep0_i[d] * Wedge[lvl][lidx][d][c]  (32 registers)
  float wt[32];
  {
    const float* WeP = Wedge + ((lvl * 4 + lidx) * 32) * 32 + c;
    int i = row & 63;
    #pragma unroll
    for (int d = 0; d < 32; d++) wt[d] = sRep0[i][d] * WeP[d * 32];
  }

  float msg[7];
  #pragma unroll
  for (int m = 0; m < 7; m++) msg[m] = 0.f;

  // ---- phase A: per-edge e, write edge, accumulate msg ----
  #pragma unroll 2
  for (int jj = 0; jj < 32; jj++) {
    int j = jh * 32 + jj;
    float radv = radp[((row * 64 + j) * 4 + lidx) * 32 + c];
    float e0 = 0.f, e1 = 0.f;
    const float* rp = &sRep0[j][0];
    #pragma unroll
    for (int d0 = 0; d0 < 32; d0 += 4) {
      float4 rv = *(const float4*)&rp[d0];
      e0 += rv.x * wt[d0] + rv.z * wt[d0 + 2];
      e1 += rv.y * wt[d0 + 1] + rv.w * wt[d0 + 3];
    }
    float e = e0 + e1;
    int eidx = ((row * 64 + j) * 4 + lidx) * 32 + c;
    if (lvl > 0) e += edge[eidx];
    float val = sCut[j] * radv * e;
    edge[eidx] = val;
    #pragma unroll
    for (int m = 0; m < 7; m++) msg[m] += val * sSphP[lidx][m][j];
  }

  // ---- phase B: reduce msg over jh ----
  #pragma unroll
  for (int m = 0; m < 7; m++) sMsgB[jh][lidx][m][c] = msg[m];
  __syncthreads();
  for (int o = tid; o < 512; o += 256) {
    int lm = o >> 5, cc = o & 31;
    int l = (lm == 0) ? 0 : (lm < 4) ? 1 : (lm < 9) ? 2 : 3;
    int bs = (l == 0) ? 0 : (l == 1) ? 1 : (l == 2) ? 4 : 9;
    int m = lm - bs;
    sMsgS[lm][cc] = sMsgB[0][l][m][cc] + sMsgB[1][l][m][cc];
  }
  __syncthreads();

  // ---- phase C: rep_new = msg@W_agg + rep_prev@W_self ----
  int d = tid & 31, lmg = tid >> 5;
  #pragma unroll
  for (int t = 0; t < 2; t++) {
    int lm = lmg + t * 8;
    int l = (lm == 0) ? 0 : (lm < 4) ? 1 : (lm < 9) ? 2 : 3;
    const float* Wa = Wagg + (lvl * 4 + l) * 32 * 32;     // [c][d]
    const float* Ws = Wself + (lvl * 4 + l) * 32 * 32;
    float acc = 0.f;
    for (int cc = 0; cc < 32; cc++) {
      acc += sMsgS[lm][cc] * Wa[cc * 32 + d];
      acc += repPrev[(row * 16 + lm) * 32 + cc] * Ws[cc * 32 + d];
    }
    repNext[(row * 16 + lm) * 32 + d] = acc;
  }
}

// ---------------- fallback fused level kernel (R3) — used if ws too small ---
__global__ __launch_bounds__(256)
void k_level_fused(int lvl, const float* __restrict__ Wrad, const float* __restrict__ Wedge,
             const float* __restrict__ Wagg, const float* __restrict__ Wself,
             const float* __restrict__ repPrev, float* __restrict__ repNext,
             float* __restrict__ edge, const float* __restrict__ cut,
             const float* __restrict__ sph, const float* __restrict__ basisG) {
  __shared__ float sWradT[4][32][60];
  __shared__ float sWtT[4][32][36];
  __shared__ float sRep0[64][32];
  __shared__ float sBasisMsg[4096];
  __shared__ float sSph[16][64];
  __shared__ float sCut[64];
  __shared__ float sMsgS[16][32];

  int row = blockIdx.x;
  int b = row >> 6;
  int tid = threadIdx.x;

  for (int idx = tid; idx < 7680; idx += 256) {
    int l = idx / 1920, rem = idx % 1920, k = rem / 32, c = rem % 32;
    sWradT[l][c][k] = Wrad[((lvl * 4 + l) * 60 + k) * 32 + c];
  }
  const float* repI = repPrev + (row * 16 + 0) * 32;
  for (int idx = tid; idx < 4096; idx += 256) {
    int l = idx >> 10, rem = idx & 1023, d = rem >> 5, c = rem & 31;
    sWtT[l][c][d] = repI[d] * Wedge[((lvl * 4 + l) * 32 + d) * 32 + c];
  }
  for (int idx = tid; idx < 2048; idx += 256) {
    int j = idx >> 5, d = idx & 31;
    sRep0[j][d] = repPrev[((b * 64 + j) * 16 + 0) * 32 + d];
  }
  for (int idx = tid; idx < 3840; idx += 256) sBasisMsg[idx] = basisG[row * 3840 + idx];
  for (int idx = tid; idx < 1024; idx += 256) (&sSph[0][0])[idx] = sph[row * 1024 + idx];
  if (tid < 64) sCut[tid] = cut[row * 64 + tid];
  __syncthreads();

  int c = tid & 31, jg = tid >> 5;
  float msg[16];
  float rad[4][8], ev[4][8];
  #pragma unroll
  for (int t = 0; t < 16; t++) msg[t] = 0.f;
  #pragma unroll
  for (int l = 0; l < 4; l++)
    #pragma unroll
    for (int jj = 0; jj < 8; jj++) { rad[l][jj] = 0.f; ev[l][jj] = 0.f; }

  for (int k0 = 0; k0 < 60; k0 += 4) {
    const float4 w0 = *(const float4*)&sWradT[0][c][k0];
    const float4 w1 = *(const float4*)&sWradT[1][c][k0];
    const float4 w2 = *(const float4*)&sWradT[2][c][k0];
    const float4 w3 = *(const float4*)&sWradT[3][c][k0];
    #pragma unroll
    for (int jj = 0; jj < 8; jj++) {
      const float4 bv = *(const float4*)&sBasisMsg[(jg * 8 + jj) * 60 + k0];
      rad[0][jj] += bv.x * w0.x + bv.y * w0.y + bv.z * w0.z + bv.w * w0.w;
      rad[1][jj] += bv.x * w1.x + bv.y * w1.y + bv.z * w1.z + bv.w * w1.w;
      rad[2][jj] += bv.x * w2.x + bv.y * w2.y + bv.z * w2.z + bv.w * w2.w;
      rad[3][jj] += bv.x * w3.x + bv.y * w3.y + bv.z * w3.z + bv.w * w3.w;
    }
  }
  for (int d0 = 0; d0 < 32; d0 += 4) {
    const float4 w0 = *(const float4*)&sWtT[0][c][d0];
    const float4 w1 = *(const float4*)&sWtT[1][c][d0];
    const float4 w2 = *(const float4*)&sWtT[2][c][d0];
    const float4 w3 = *(const float4*)&sWtT[3][c][d0];
    #pragma unroll
    for (int jj = 0; jj < 8; jj++) {
      const float4 rv = *(const float4*)&sRep0[jg * 8 + jj][d0];
      ev[0][jj] += rv.x * w0.x + rv.y * w0.y + rv.z * w0.z + rv.w * w0.w;
      ev[1][jj] += rv.x * w1.x + rv.y * w1.y + rv.z * w1.z + rv.w * w1.w;
      ev[2][jj] += rv.x * w2.x + rv.y * w2.y + rv.z * w2.z + rv.w * w2.w;
      ev[3][jj] += rv.x * w3.x + rv.y * w3.y + rv.z * w3.z + rv.w * w3.w;
    }
  }
  #pragma unroll
  for (int l = 0; l < 4; l++) {
    const int base = (l == 0) ? 0 : (l == 1) ? 1 : (l == 2) ? 4 : 9;
    #pragma unroll
    for (int jj = 0; jj < 8; jj++) {
      int j = jg * 8 + jj;
      int eidx = ((row * 64 + j) * 4 + l) * 32 + c;
      float e = ev[l][jj];
      if (lvl > 0) e += edge[eidx];
      float val = sCut[j] * rad[l][jj] * e;
      edge[eidx] = val;
      #pragma unroll
      for (int m = 0; m < 2 * l + 1; m++)
        msg[base + m] += val * sSph[base + m][j];
    }
  }
  __syncthreads();

  float* sMsg = sBasisMsg;
  #pragma unroll
  for (int t = 0; t < 16; t++) sMsg[(jg * 16 + t) * 32 + c] = msg[t];
  __syncthreads();
  for (int o = tid; o < 512; o += 256) {
    int lm = o >> 5, cc = o & 31;
    float acc = 0.f;
    #pragma unroll
    for (int g = 0; g < 8; g++) acc += sMsg[(g * 16 + lm) * 32 + cc];
    sMsgS[lm][cc] = acc;
  }
  __syncthreads();

  int d = tid & 31, lmg = tid >> 5;
  #pragma unroll
  for (int t = 0; t < 2; t++) {
    int lm = lmg + t * 8;
    int l = (lm == 0) ? 0 : (lm < 4) ? 1 : (lm < 9) ? 2 : 3;
    const float* Wa = Wagg + (lvl * 4 + l) * 32 * 32;
    const float* Ws = Wself + (lvl * 4 + l) * 32 * 32;
    float acc = 0.f;
    for (int cc = 0; cc < 32; cc++) {
      acc += sMsgS[lm][cc] * Wa[cc * 32 + d];
      acc += repPrev[(row * 16 + lm) * 32 + cc] * Ws[cc * 32 + d];
    }
    repNext[(row * 16 + lm) * 32 + d] = acc;
  }
}

// ---------------- F1: per-atom invariant scalars . W_top -> partial ---------
__global__ void k_scalars(const float* __restrict__ repAll, const float* __restrict__ Wtop,
                          float* __restrict__ partial) {
  int an = blockIdx.x;                  // b*64 + n, 1024 blocks
  int tid = threadIdx.x;                // 128 threads
  __shared__ float red[128];
  float p = 0.f;
  for (int f = tid; f < 512; f += 128) {
    int lvl = f >> 7;
    int rem = f & 127;
    int l = rem >> 5;
    int c = rem & 31;
    const float* repB = repAll + (lvl + 1) * REPSZ + an * 512;   // [16][32] block
    int base = (l == 0) ? 0 : (l == 1) ? 1 : (l == 2) ? 4 : 9;
    float v;
    if (l == 0) {
      v = repB[c];
    } else {
      float s2 = 0.f;
      for (int m = 0; m < 2 * l + 1; m++) {
        float t = repB[(base + m) * 32 + c];
        s2 += t * t;
      }
      v = sqrtf(s2 + 1e-12f);
    }
    p += v * Wtop[f];
  }
  red[tid] = p;
  __syncthreads();
  for (int s = 64; s > 0; s >>= 1) {
    if (tid < s) red[tid] += red[tid + s];
    __syncthreads();
  }
  if (tid == 0) partial[an] = red[0];
}

// ---------------- F2: reduce partials per batch -----------------------------
__global__ void k_out(const float* __restrict__ partial, const float* __restrict__ btop,
                      float* __restrict__ out) {
  int b = blockIdx.x;                   // 16 blocks x 64 threads (1 wave)
  int tid = threadIdx.x;
  float v = partial[b * 64 + tid];
  #pragma unroll
  for (int o = 32; o > 0; o >>= 1) v += __shfl_down(v, o, 64);
  if (tid == 0) out[b] = v + btop[0];
}

// ---------------- launch ----------------------------------------------------
extern "C" void kernel_launch(void* const* d_in, const int* in_sizes, int n_in,
                              void* d_out, int out_size, void* d_ws, size_t ws_size,
                              hipStream_t stream) {
  const float* positions = (const float*)d_in[0];
  const float* one_hot   = (const float*)d_in[1];
  const int*   charges   = (const int*)d_in[2];
  const float* W_in   = (const float*)d_in[5];
  const float* b_in   = (const float*)d_in[6];
  const float* W_rad  = (const float*)d_in[7];
  const float* W_edge = (const float*)d_in[8];
  const float* W_agg  = (const float*)d_in[9];
  const float* W_self = (const float*)d_in[10];
  const float* W_top  = (const float*)d_in[11];
  const float* b_top  = (const float*)d_in[12];
  float* out = (float*)d_out;
  float* ws = (float*)d_ws;

  float* rep    = ws + OFF_REP;
  float* edge   = ws + OFF_EDGE;
  float* cutp   = ws + OFF_CUT;
  float* sphp   = ws + OFF_SPH;
  float* basisp = ws + OFF_BASIS;
  float* radp   = ws + OFF_RAD;
  float* partial = ws + OFF_PART;   // aliases edge (dead after levels)

  bool big = ws_size >= (size_t)NEED_FLOATS * sizeof(float);

  k_init<<<2048, 256, 0, stream>>>(one_hot, charges, W_in, b_in, rep);
  k_geom<<<1024, 64, 0, stream>>>(positions, cutp, sphp, basisp);
  for (int lvl = 0; lvl < NLVL; lvl++) {
    if (big) {
      k_rad<<<1024, 256, 0, stream>>>(lvl, W_rad, basisp, radp);
      k_level<<<1024, 256, 0, stream>>>(lvl, W_edge, W_agg, W_self,
                                        rep + lvl * REPSZ, rep + (lvl + 1) * REPSZ,
                                        edge, cutp, sphp, radp);
    } else {
      k_level_fused<<<1024, 256, 0, stream>>>(lvl, W_rad, W_edge, W_agg, W_self,
                                        rep + lvl * REPSZ, rep + (lvl + 1) * REPSZ,
                                        edge, cutp, sphp, basisp);
    }
  }
  k_scalars<<<1024, 128, 0, stream>>>(rep, W_top, partial);
  k_out<<<16, 64, 0, stream>>>(partial, b_top, out);
}